// Round 4
// baseline (511.548 us; speedup 1.0000x reference)
//
#include <hip/hip_runtime.h>
#include <hip/hip_bf16.h>
#include <math.h>

// Problem constants (reference: B=8, S=1024, D=1024, E=8, F=2048, capacity 2 -> k=256)
#define B_   8
#define S_   1024
#define D_   1024
#define E_   8
#define F_   2048
#define KCAP 256

typedef __bf16 bf16x8 __attribute__((ext_vector_type(8)));
typedef float  floatx4 __attribute__((ext_vector_type(4)));
typedef unsigned short ushortx8 __attribute__((ext_vector_type(8)));

// ---- fp32 -> bf16 round-to-nearest-even (no NaN in this data) ----
__device__ __forceinline__ unsigned short f2b(float f) {
    union { float f; unsigned int u; } v; v.f = f;
    unsigned int u = v.u;
    u += 0x7fffu + ((u >> 16) & 1u);
    return (unsigned short)(u >> 16);
}
__device__ __forceinline__ float b2f(unsigned short u) {
    union { unsigned int u; float f; } v; v.u = ((unsigned)u) << 16; return v.f;
}

__device__ __forceinline__ void gl_lds16(const void* g, void* l) {
    __builtin_amdgcn_global_load_lds(
        (const __attribute__((address_space(1))) void*)g,
        (__attribute__((address_space(3))) void*)l, 16, 0, 0);
}

// ---------------- 1. router: logits + softmax (fp32) + fused x->bf16 cast (vectorized) ----------------
// probs layout: [B][E][S] (transposed for per-(b,e) top-k). One wave per token; lane owns 4 consecutive d.
__global__ void router_kernel(const float* __restrict__ x, const float* __restrict__ cw,
                              float* __restrict__ probs, unsigned short* __restrict__ xb) {
    int gid  = blockIdx.x * 256 + threadIdx.x;
    int wave = gid >> 6;
    int lane = gid & 63;
    int b = wave >> 10;                                // S_=1024
    int s = wave & (S_ - 1);
    const float* xrow = x + ((size_t)b * S_ + s) * D_;
    unsigned short* xbrow = xb + ((size_t)b * S_ + s) * D_;
    float acc[E_];
#pragma unroll
    for (int e = 0; e < E_; e++) acc[e] = 0.f;
#pragma unroll
    for (int it = 0; it < D_ / 256; it++) {
        int i = it * 256 + lane * 4;
        float4 xv = *(const float4*)(xrow + i);
        ushort4 o;
        o.x = f2b(xv.x); o.y = f2b(xv.y); o.z = f2b(xv.z); o.w = f2b(xv.w);
        *(ushort4*)(xbrow + i) = o;                    // fused cast, 8B/lane stores
#pragma unroll
        for (int e = 0; e < E_; e++) {
            float4 wv = *(const float4*)(cw + e * D_ + i);   // 32KB table, L1/L2-resident
            acc[e] = fmaf(xv.x, wv.x, fmaf(xv.y, wv.y, fmaf(xv.z, wv.z, fmaf(xv.w, wv.w, acc[e]))));
        }
    }
#pragma unroll
    for (int e = 0; e < E_; e++) {
        float v = acc[e];
#pragma unroll
        for (int off = 32; off >= 1; off >>= 1) v += __shfl_down(v, off, 64);
        acc[e] = v;
    }
    if (lane == 0) {
        float m = acc[0];
#pragma unroll
        for (int e = 1; e < E_; e++) m = fmaxf(m, acc[e]);
        float sum = 0.f;
#pragma unroll
        for (int e = 0; e < E_; e++) { acc[e] = __expf(acc[e] - m); sum += acc[e]; }
        float inv = 1.f / sum;
#pragma unroll
        for (int e = 0; e < E_; e++) probs[((size_t)b * E_ + e) * S_ + s] = acc[e] * inv;
    }
}

// ---------------- 2. top-k by rank counting + fused inverse-map build ----------------
// Matches lax.top_k tie-break (value desc, index asc). Block (b,e) exclusively owns
// Pmap column [b][.][e]: zero it, then write slot+1 at chosen tokens (ordered by barrier).
__global__ void topk_kernel(const float* __restrict__ probs, int* __restrict__ I,
                            float* __restrict__ G, unsigned short* __restrict__ Pmap) {
    int be = blockIdx.x;                               // one block per (b,e)
    int b = be >> 3, eidx = be & 7;
    const float* rowp = probs + (size_t)be * S_;
    __shared__ float p[S_];
    for (int i = threadIdx.x; i < S_; i += 256) {
        p[i] = rowp[i];
        Pmap[((size_t)(b * S_ + i)) * E_ + eidx] = 0;  // zero own column (no separate memset)
    }
    __syncthreads();
    int s0 = threadIdx.x, s1 = s0 + 256, s2 = s0 + 512, s3 = s0 + 768;
    float p0 = p[s0], p1 = p[s1], p2 = p[s2], p3 = p[s3];
    int r0 = 0, r1 = 0, r2 = 0, r3 = 0;
    for (int t = 0; t < S_; t++) {
        float pt = p[t];                               // LDS broadcast, conflict-free
        r0 += (pt > p0) || (pt == p0 && t < s0);
        r1 += (pt > p1) || (pt == p1 && t < s1);
        r2 += (pt > p2) || (pt == p2 && t < s2);
        r3 += (pt > p3) || (pt == p3 && t < s3);
    }
    int base = be * KCAP;
    if (r0 < KCAP) { I[base + r0] = s0; G[base + r0] = p0; Pmap[((size_t)(b * S_ + s0)) * E_ + eidx] = (unsigned short)(r0 + 1); }
    if (r1 < KCAP) { I[base + r1] = s1; G[base + r1] = p1; Pmap[((size_t)(b * S_ + s1)) * E_ + eidx] = (unsigned short)(r1 + 1); }
    if (r2 < KCAP) { I[base + r2] = s2; G[base + r2] = p2; Pmap[((size_t)(b * S_ + s2)) * E_ + eidx] = (unsigned short)(r2 + 1); }
    if (r3 < KCAP) { I[base + r3] = s3; G[base + r3] = p3; Pmap[((size_t)(b * S_ + s3)) * E_ + eidx] = (unsigned short)(r3 + 1); }
}

// ---------------- 3. batched transpose + cast: in [E][R][C] fp32 -> out [E][C][R] bf16 ----------------
// 256 linear threads, 32x32 tile; float4 coalesced reads, ushort4 vectorized writes.
__global__ void transpose_cvt_kernel(const float* __restrict__ in, unsigned short* __restrict__ out,
                                     int R, int C) {
    __shared__ float tile[32][33];                    // +1 pad
    int e = blockIdx.z;
    int c0 = blockIdx.x * 32, r0 = blockIdx.y * 32;
    const float* ine = in + (size_t)e * R * C;
    unsigned short* oute = out + (size_t)e * R * C;
    int tid = threadIdx.x;
    int row = tid >> 3, cs = tid & 7;
    float4 v = *(const float4*)(ine + (size_t)(r0 + row) * C + c0 + cs * 4);
    tile[row][cs * 4 + 0] = v.x; tile[row][cs * 4 + 1] = v.y;
    tile[row][cs * 4 + 2] = v.z; tile[row][cs * 4 + 3] = v.w;
    __syncthreads();
    int c = tid >> 3, rq = tid & 7;
    ushort4 o;
    o.x = f2b(tile[rq * 4 + 0][c]); o.y = f2b(tile[rq * 4 + 1][c]);
    o.z = f2b(tile[rq * 4 + 2][c]); o.w = f2b(tile[rq * 4 + 3][c]);
    *(ushort4*)(oute + (size_t)(c0 + c) * R + r0 + rq * 4) = o;
}

// ======== GEMM core notes ========
// BK=64. LDS tile = 128 rows x 64 k bf16 = 16 KB/matrix; staged in 4 sweeps of 256 x 16B.
// Bank-conflict-free by construction: a row's 128B slab is 16B-segment-permuted with
// seg_stored(c) = c ^ (row & 7). Row term contributes 0 mod 32 banks (128B row stride),
// so each frag ds_read_b128 covers all 8 bank-groups exactly twice (2-way = free, m136).
// global_load_lds keeps its required lane-linear LDS destination; only the per-lane
// GLOBAL address is permuted (same cache lines touched -> coalescing unaffected).

// ---------------- 4. GEMM1: H[be] = silu(gather(x, I[be]) @ w1[e]) ----------------
__global__ __launch_bounds__(256, 4) void gemm1_kernel(
    const unsigned short* __restrict__ xb,   // [B][S][D] bf16
    const unsigned short* __restrict__ w1t,  // [E][F][D] bf16
    const int* __restrict__ I,               // [B][E][KCAP]
    unsigned short* __restrict__ H)          // [B*E][KCAP][F] bf16
{
    const int be = blockIdx.x >> 5;
    const int t5 = blockIdx.x & 31;
    const int mt = t5 & 1;          // 2 m-tiles (256/128)
    const int nt = t5 >> 1;         // 16 n-tiles (2048/128)
    const int b  = be >> 3;
    const int e  = be & 7;
    const int tid = threadIdx.x;

    __shared__ __align__(16) unsigned short Asm[128 * 64];  // 16 KB
    __shared__ __align__(16) unsigned short Bsm[128 * 64];  // 16 KB
    __shared__ unsigned int ArowS[128];

    if (tid < 128) {
        int tok = I[(size_t)be * KCAP + mt * 128 + tid];
        ArowS[tid] = (unsigned)((b * S_ + tok) * D_);
    }
    __syncthreads();

    const int r8   = tid >> 3;                       // 0..31 (row within sweep)
    const int kseg = (tid & 7) ^ (r8 & 7);           // permuted 16B segment
    unsigned aoffW[4];
#pragma unroll
    for (int w = 0; w < 4; w++) aoffW[w] = ArowS[w * 32 + r8] + kseg * 8;
    const size_t boff0 = ((size_t)e * F_ + nt * 128 + r8) * D_ + kseg * 8;

    const int lane = tid & 63;
    const int wv   = tid >> 6;
    const int wm   = (wv & 1) * 64;
    const int wn   = (wv >> 1) * 64;
    const int l15  = lane & 15;
    const int quad = lane >> 4;
    const int x0   = (quad ^ (l15 & 7)) * 8;         // h=0 swizzled seg offset (elements)

    int aoffs[4], boffs[4];
#pragma unroll
    for (int i = 0; i < 4; i++) {
        aoffs[i] = (wm + i * 16 + l15) * 64 + x0;
        boffs[i] = (wn + i * 16 + l15) * 64 + x0;
    }

    floatx4 acc[4][4];
#pragma unroll
    for (int i = 0; i < 4; i++)
#pragma unroll
        for (int j = 0; j < 4; j++) acc[i][j] = (floatx4){0.f, 0.f, 0.f, 0.f};

    for (int k0 = 0; k0 < D_; k0 += 64) {
#pragma unroll
        for (int w = 0; w < 4; w++) {
            gl_lds16(xb  + aoffW[w] + k0,                    &Asm[(w * 256 + tid) * 8]);
            gl_lds16(w1t + boff0 + (size_t)w * 32 * D_ + k0, &Bsm[(w * 256 + tid) * 8]);
        }
        __syncthreads();
        bf16x8 af[4], bfr[4];
#pragma unroll
        for (int i = 0; i < 4; i++) {                 // k-half 0
            af[i]  = *(const bf16x8*)&Asm[aoffs[i]];
            bfr[i] = *(const bf16x8*)&Bsm[boffs[i]];
        }
#pragma unroll
        for (int i = 0; i < 4; i++)
#pragma unroll
            for (int j = 0; j < 4; j++)
                acc[i][j] = __builtin_amdgcn_mfma_f32_16x16x32_bf16(af[i], bfr[j], acc[i][j], 0, 0, 0);
#pragma unroll
        for (int i = 0; i < 4; i++) {                 // k-half 1: seg offset = x0 ^ 4 -> elem ^ 32
            af[i]  = *(const bf16x8*)&Asm[aoffs[i] ^ 32];
            bfr[i] = *(const bf16x8*)&Bsm[boffs[i] ^ 32];
        }
#pragma unroll
        for (int i = 0; i < 4; i++)
#pragma unroll
            for (int j = 0; j < 4; j++)
                acc[i][j] = __builtin_amdgcn_mfma_f32_16x16x32_bf16(af[i], bfr[j], acc[i][j], 0, 0, 0);
        __syncthreads();
    }

    // epilogue: silu -> H (bf16). C/D layout: row = quad*4+r, col = lane&15 (m89-verified)
    unsigned short* Hbe = H + (size_t)be * KCAP * F_;
#pragma unroll
    for (int i = 0; i < 4; i++) {
#pragma unroll
        for (int r = 0; r < 4; r++) {
            int m = mt * 128 + wm + i * 16 + quad * 4 + r;
            unsigned short* hrow = Hbe + (size_t)m * F_ + nt * 128;
#pragma unroll
            for (int j = 0; j < 4; j++) {
                float v = acc[i][j][r];
                float sv = v / (1.f + __expf(-v));
                hrow[wn + j * 16 + l15] = f2b(sv);
            }
        }
    }
}

// ---------------- 5. GEMM2: xmlp[be] = H[be] @ w2[e]  (bf16 out, no atomics) ----------------
__global__ __launch_bounds__(256, 4) void gemm2_kernel(
    const unsigned short* __restrict__ H,    // [B*E][KCAP][F] bf16
    const unsigned short* __restrict__ w2t,  // [E][D][F] bf16
    unsigned short* __restrict__ xmlp)       // [B*E][KCAP][D] bf16
{
    const int be = blockIdx.x >> 4;
    const int t4 = blockIdx.x & 15;
    const int mt = t4 & 1;          // 2 m-tiles
    const int nt = t4 >> 1;         // 8 n-tiles (1024/128)
    const int e  = be & 7;
    const int tid = threadIdx.x;

    __shared__ __align__(16) unsigned short Asm[128 * 64];
    __shared__ __align__(16) unsigned short Bsm[128 * 64];

    const int r8   = tid >> 3;
    const int kseg = (tid & 7) ^ (r8 & 7);
    const size_t aoff0 = ((size_t)be * KCAP + mt * 128 + r8) * F_ + kseg * 8;
    const size_t boff0 = ((size_t)e * D_ + nt * 128 + r8) * F_ + kseg * 8;

    const int lane = tid & 63;
    const int wv   = tid >> 6;
    const int wm   = (wv & 1) * 64;
    const int wn   = (wv >> 1) * 64;
    const int l15  = lane & 15;
    const int quad = lane >> 4;
    const int x0   = (quad ^ (l15 & 7)) * 8;

    int aoffs[4], boffs[4];
#pragma unroll
    for (int i = 0; i < 4; i++) {
        aoffs[i] = (wm + i * 16 + l15) * 64 + x0;
        boffs[i] = (wn + i * 16 + l15) * 64 + x0;
    }

    floatx4 acc[4][4];
#pragma unroll
    for (int i = 0; i < 4; i++)
#pragma unroll
        for (int j = 0; j < 4; j++) acc[i][j] = (floatx4){0.f, 0.f, 0.f, 0.f};

    for (int k0 = 0; k0 < F_; k0 += 64) {
#pragma unroll
        for (int w = 0; w < 4; w++) {
            gl_lds16(H   + aoff0 + (size_t)w * 32 * F_ + k0, &Asm[(w * 256 + tid) * 8]);
            gl_lds16(w2t + boff0 + (size_t)w * 32 * F_ + k0, &Bsm[(w * 256 + tid) * 8]);
        }
        __syncthreads();
        bf16x8 af[4], bfr[4];
#pragma unroll
        for (int i = 0; i < 4; i++) {
            af[i]  = *(const bf16x8*)&Asm[aoffs[i]];
            bfr[i] = *(const bf16x8*)&Bsm[boffs[i]];
        }
#pragma unroll
        for (int i = 0; i < 4; i++)
#pragma unroll
            for (int j = 0; j < 4; j++)
                acc[i][j] = __builtin_amdgcn_mfma_f32_16x16x32_bf16(af[i], bfr[j], acc[i][j], 0, 0, 0);
#pragma unroll
        for (int i = 0; i < 4; i++) {
            af[i]  = *(const bf16x8*)&Asm[aoffs[i] ^ 32];
            bfr[i] = *(const bf16x8*)&Bsm[boffs[i] ^ 32];
        }
#pragma unroll
        for (int i = 0; i < 4; i++)
#pragma unroll
            for (int j = 0; j < 4; j++)
                acc[i][j] = __builtin_amdgcn_mfma_f32_16x16x32_bf16(af[i], bfr[j], acc[i][j], 0, 0, 0);
        __syncthreads();
    }

    // epilogue: plain coalesced bf16 stores (combine kernel applies G and scatters)
    unsigned short* Xbe = xmlp + (size_t)be * KCAP * D_;
#pragma unroll
    for (int i = 0; i < 4; i++) {
#pragma unroll
        for (int r = 0; r < 4; r++) {
            int m = mt * 128 + wm + i * 16 + quad * 4 + r;
            unsigned short* orow = Xbe + (size_t)m * D_ + nt * 128;
#pragma unroll
            for (int j = 0; j < 4; j++)
                orow[wn + j * 16 + l15] = f2b(acc[i][j][r]);
        }
    }
}

// ---------------- 6. combine: out[b,s,:] = sum_e Pmap-hit G * xmlp-row (each token written once) -------
__global__ void combine_kernel(const unsigned short* __restrict__ xmlp, // [B*E][KCAP][D] bf16
                               const unsigned short* __restrict__ Pmap, // [B][S][E] slot+1
                               const float* __restrict__ G,             // [B*E][KCAP]
                               float* __restrict__ out) {               // [B][S][D] fp32
    int gid  = blockIdx.x * 256 + threadIdx.x;
    int wave = gid >> 6;                               // token id b*S+s
    int lane = gid & 63;
    int b = wave >> 10;
    float acc[16];
#pragma unroll
    for (int i = 0; i < 16; i++) acc[i] = 0.f;
    const unsigned short* pm = Pmap + (size_t)wave * E_;
#pragma unroll
    for (int e = 0; e < E_; e++) {
        int pe = pm[e];
        if (pe) {
            int beslot = (b * E_ + e) * KCAP + (pe - 1);
            float g = G[beslot];
            const unsigned short* rw = xmlp + (size_t)beslot * D_ + lane * 16;
            ushortx8 r0 = *(const ushortx8*)(rw);
            ushortx8 r1 = *(const ushortx8*)(rw + 8);
#pragma unroll
            for (int i = 0; i < 8; i++) {
                acc[i]     = fmaf(g, b2f(r0[i]), acc[i]);
                acc[8 + i] = fmaf(g, b2f(r1[i]), acc[8 + i]);
            }
        }
    }
    float* orow = out + (size_t)wave * D_ + lane * 16;
    ((float4*)orow)[0] = make_float4(acc[0],  acc[1],  acc[2],  acc[3]);
    ((float4*)orow)[1] = make_float4(acc[4],  acc[5],  acc[6],  acc[7]);
    ((float4*)orow)[2] = make_float4(acc[8],  acc[9],  acc[10], acc[11]);
    ((float4*)orow)[3] = make_float4(acc[12], acc[13], acc[14], acc[15]);
}

// ---------------- launch ----------------
extern "C" void kernel_launch(void* const* d_in, const int* in_sizes, int n_in,
                              void* d_out, int out_size, void* d_ws, size_t ws_size,
                              hipStream_t stream) {
    const float* x  = (const float*)d_in[0];
    const float* cw = (const float*)d_in[1];
    const float* w1 = (const float*)d_in[2];
    const float* w2 = (const float*)d_in[3];
    float* out = (float*)d_out;

    // workspace layout (bytes), total 151,519,232.
    // wT shared between w1t (gemm1) and w2t (gemm2) -- transpose of w2 runs AFTER gemm1.
    char* ws = (char*)d_ws;
    float*          probs = (float*)(ws);                        //   0.26 MB  [B][E][S]
    int*            Ibuf  = (int*)(ws + 262144);                 //  64 KB     [B][E][256]
    float*          Gbuf  = (float*)(ws + 327680);               //  64 KB
    unsigned short* Pmap  = (unsigned short*)(ws + 393216);      // 128 KB     [B][S][E]
    unsigned short* xb    = (unsigned short*)(ws + 524288);      //  16.78 MB  x bf16
    unsigned short* wT    = (unsigned short*)(ws + 17301504);    //  33.55 MB  [E][F][D] then [E][D][F]
    unsigned short* Hbuf  = (unsigned short*)(ws + 50855936);    //  67.11 MB  [B*E][256][F]
    unsigned short* xmlp  = (unsigned short*)(ws + 117964800);   //  33.55 MB  [B*E][256][D]

    router_kernel<<<(B_ * S_ * 64) / 256, 256, 0, stream>>>(x, cw, probs, xb);
    topk_kernel<<<B_ * E_, 256, 0, stream>>>(probs, Ibuf, Gbuf, Pmap);
    transpose_cvt_kernel<<<dim3(F_ / 32, D_ / 32, E_), 256, 0, stream>>>(w1, wT, D_, F_);
    gemm1_kernel<<<B_ * E_ * 2 * (F_ / 128), 256, 0, stream>>>(xb, wT, Ibuf, Hbuf);
    transpose_cvt_kernel<<<dim3(D_ / 32, F_ / 32, E_), 256, 0, stream>>>(w2, wT, F_, D_);
    gemm2_kernel<<<B_ * E_ * 2 * (D_ / 128), 256, 0, stream>>>(Hbuf, wT, xmlp);
    combine_kernel<<<(B_ * S_ * 64) / 256, 256, 0, stream>>>(xmlp, Pmap, Gbuf, out);
}

// Round 5
// 366.062 us; speedup vs baseline: 1.3974x; 1.3974x over previous
//
#include <hip/hip_runtime.h>
#include <hip/hip_bf16.h>
#include <math.h>

// Problem constants (reference: B=8, S=1024, D=1024, E=8, F=2048, capacity 2 -> k=256)
#define B_   8
#define S_   1024
#define D_   1024
#define E_   8
#define F_   2048
#define KCAP 256

typedef __bf16 bf16x8 __attribute__((ext_vector_type(8)));
typedef float  floatx4 __attribute__((ext_vector_type(4)));
typedef unsigned short ushortx8 __attribute__((ext_vector_type(8)));

// ---- fp32 -> bf16 round-to-nearest-even (no NaN in this data) ----
__device__ __forceinline__ unsigned short f2b(float f) {
    union { float f; unsigned int u; } v; v.f = f;
    unsigned int u = v.u;
    u += 0x7fffu + ((u >> 16) & 1u);
    return (unsigned short)(u >> 16);
}
__device__ __forceinline__ float b2f(unsigned short u) {
    union { unsigned int u; float f; } v; v.u = ((unsigned)u) << 16; return v.f;
}

__device__ __forceinline__ void gl_lds16(const void* g, void* l) {
    __builtin_amdgcn_global_load_lds(
        (const __attribute__((address_space(1))) void*)g,
        (__attribute__((address_space(3))) void*)l, 16, 0, 0);
}

// sortable key: probs > 0 so float bits are monotonic; secondary index asc
// (larger (1023-s) wins ties -> smaller s, matching lax.top_k).
__device__ __forceinline__ unsigned long long topk_key(float p, int s) {
    return (((unsigned long long)__float_as_uint(p)) << 10) | (unsigned)(S_ - 1 - s);
}

// ---------------- 1. router: logits + softmax (fp32) + fused x->bf16 cast (vectorized) ----------------
// probs layout: [B][E][S] (transposed for per-(b,e) top-k). One wave per token; lane owns 4 consecutive d.
__global__ void router_kernel(const float* __restrict__ x, const float* __restrict__ cw,
                              float* __restrict__ probs, unsigned short* __restrict__ xb) {
    int gid  = blockIdx.x * 256 + threadIdx.x;
    int wave = gid >> 6;
    int lane = gid & 63;
    int b = wave >> 10;                                // S_=1024
    int s = wave & (S_ - 1);
    const float* xrow = x + ((size_t)b * S_ + s) * D_;
    unsigned short* xbrow = xb + ((size_t)b * S_ + s) * D_;
    float acc[E_];
#pragma unroll
    for (int e = 0; e < E_; e++) acc[e] = 0.f;
#pragma unroll
    for (int it = 0; it < D_ / 256; it++) {
        int i = it * 256 + lane * 4;
        float4 xv = *(const float4*)(xrow + i);
        ushort4 o;
        o.x = f2b(xv.x); o.y = f2b(xv.y); o.z = f2b(xv.z); o.w = f2b(xv.w);
        *(ushort4*)(xbrow + i) = o;                    // fused cast, 8B/lane stores
#pragma unroll
        for (int e = 0; e < E_; e++) {
            float4 wv = *(const float4*)(cw + e * D_ + i);   // 32KB table, L1/L2-resident
            acc[e] = fmaf(xv.x, wv.x, fmaf(xv.y, wv.y, fmaf(xv.z, wv.z, fmaf(xv.w, wv.w, acc[e]))));
        }
    }
#pragma unroll
    for (int e = 0; e < E_; e++) {
        float v = acc[e];
#pragma unroll
        for (int off = 32; off >= 1; off >>= 1) v += __shfl_down(v, off, 64);
        acc[e] = v;
    }
    if (lane == 0) {
        float m = acc[0];
#pragma unroll
        for (int e = 1; e < E_; e++) m = fmaxf(m, acc[e]);
        float sum = 0.f;
#pragma unroll
        for (int e = 0; e < E_; e++) { acc[e] = __expf(acc[e] - m); sum += acc[e]; }
        float inv = 1.f / sum;
#pragma unroll
        for (int e = 0; e < E_; e++) probs[((size_t)b * E_ + e) * S_ + s] = acc[e] * inv;
    }
}

// ---------------- 2a. partial rank counting: 256 blocks = 64 (b,e) x 4 t-chunks ----------------
// Thread tid holds 4 candidate keys; scans its 256-key LDS chunk; one u64 cmp per pair.
__global__ void topk_rank_kernel(const float* __restrict__ probs, int* __restrict__ R4) {
    int g  = blockIdx.x;
    int be = g >> 2, c = g & 3;
    int tid = threadIdx.x;
    const float* rowp = probs + (size_t)be * S_;
    __shared__ unsigned long long kc[256];
    {
        int t = c * 256 + tid;
        kc[tid] = topk_key(rowp[t], t);
    }
    unsigned long long k[4];
    int r[4] = {0, 0, 0, 0};
#pragma unroll
    for (int q = 0; q < 4; q++) k[q] = topk_key(rowp[q * 256 + tid], q * 256 + tid);
    __syncthreads();
#pragma unroll 8
    for (int t = 0; t < 256; t++) {
        unsigned long long kt = kc[t];                 // LDS broadcast
#pragma unroll
        for (int q = 0; q < 4; q++) r[q] += (kt > k[q]);
    }
    int* Rb = R4 + (g << 10);                          // [be*4+c][1024]
#pragma unroll
    for (int q = 0; q < 4; q++) Rb[q * 256 + tid] = r[q];
}

// ---------------- 2b. finalize: sum partials, emit I/G and inverse map Pmap ----------------
__global__ void topk_finalize_kernel(const float* __restrict__ probs, const int* __restrict__ R4,
                                     int* __restrict__ I, float* __restrict__ G,
                                     unsigned short* __restrict__ Pmap) {
    int be = blockIdx.x;                               // one block per (b,e); owns Pmap column e
    int b = be >> 3, e = be & 7;
    int tid = threadIdx.x;
    for (int i = tid; i < S_; i += 256)
        Pmap[((size_t)(b * S_ + i)) * E_ + e] = 0;
    __syncthreads();
    const float* rowp = probs + (size_t)be * S_;
    const int* Rb = R4 + (be << 12);
#pragma unroll
    for (int q = 0; q < 4; q++) {
        int s = q * 256 + tid;
        int rank = Rb[s] + Rb[1024 + s] + Rb[2048 + s] + Rb[3072 + s];
        if (rank < KCAP) {
            I[be * KCAP + rank] = s;
            G[be * KCAP + rank] = rowp[s];
            Pmap[((size_t)(b * S_ + s)) * E_ + e] = (unsigned short)(rank + 1);
        }
    }
}

// ---------------- 3. batched transpose + cast: in [E][R][C] fp32 -> out [E][C][R] bf16 ----------------
__global__ void transpose_cvt_kernel(const float* __restrict__ in, unsigned short* __restrict__ out,
                                     int R, int C) {
    __shared__ float tile[32][33];                    // +1 pad
    int e = blockIdx.z;
    int c0 = blockIdx.x * 32, r0 = blockIdx.y * 32;
    const float* ine = in + (size_t)e * R * C;
    unsigned short* oute = out + (size_t)e * R * C;
    int tid = threadIdx.x;
    int row = tid >> 3, cs = tid & 7;
    float4 v = *(const float4*)(ine + (size_t)(r0 + row) * C + c0 + cs * 4);
    tile[row][cs * 4 + 0] = v.x; tile[row][cs * 4 + 1] = v.y;
    tile[row][cs * 4 + 2] = v.z; tile[row][cs * 4 + 3] = v.w;
    __syncthreads();
    int c = tid >> 3, rq = tid & 7;
    ushort4 o;
    o.x = f2b(tile[rq * 4 + 0][c]); o.y = f2b(tile[rq * 4 + 1][c]);
    o.z = f2b(tile[rq * 4 + 2][c]); o.w = f2b(tile[rq * 4 + 3][c]);
    *(ushort4*)(oute + (size_t)(c0 + c) * R + r0 + rq * 4) = o;
}

// ======== GEMM core notes ========
// BK=64, 128x128 tile, 4 sweeps of 256 x 16B staging, bank-conflict-free via 16B-segment
// permutation seg_stored(c) = c ^ (row & 7) (verified round 4: SQ_LDS_BANK_CONFLICT = 0).
// XCD swizzle: blockIdx % 8 selects the (b,e) group's e, so all tiles of one (b,e) -- and
// all 8 b's sharing w*t[e] (4 MB = one XCD L2) -- dispatch to the same XCD for L2 reuse.

// ---------------- 4. GEMM1: H[be] = silu(gather(x, I[be]) @ w1[e]) ----------------
__global__ __launch_bounds__(256, 4) void gemm1_kernel(
    const unsigned short* __restrict__ xb,   // [B][S][D] bf16
    const unsigned short* __restrict__ w1t,  // [E][F][D] bf16
    const int* __restrict__ I,               // [B][E][KCAP]
    unsigned short* __restrict__ H)          // [B*E][KCAP][F] bf16
{
    const int g  = blockIdx.x;               // 2048 = 8 xcd * 8 b * 32 tiles
    const int e  = g & 7;                    // XCD id
    const int rr = g >> 3;
    const int b  = rr >> 5;
    const int t5 = rr & 31;
    const int be = b * 8 + e;
    const int mt = t5 & 1;          // 2 m-tiles (256/128)
    const int nt = t5 >> 1;         // 16 n-tiles (2048/128)
    const int tid = threadIdx.x;

    __shared__ __align__(16) unsigned short Asm[128 * 64];  // 16 KB
    __shared__ __align__(16) unsigned short Bsm[128 * 64];  // 16 KB
    __shared__ unsigned int ArowS[128];

    if (tid < 128) {
        int tok = I[(size_t)be * KCAP + mt * 128 + tid];
        ArowS[tid] = (unsigned)((b * S_ + tok) * D_);
    }
    __syncthreads();

    const int r8   = tid >> 3;                       // 0..31 (row within sweep)
    const int kseg = (tid & 7) ^ (r8 & 7);           // permuted 16B segment
    unsigned aoffW[4];
#pragma unroll
    for (int w = 0; w < 4; w++) aoffW[w] = ArowS[w * 32 + r8] + kseg * 8;
    const size_t boff0 = ((size_t)e * F_ + nt * 128 + r8) * D_ + kseg * 8;

    const int lane = tid & 63;
    const int wv   = tid >> 6;
    const int wm   = (wv & 1) * 64;
    const int wn   = (wv >> 1) * 64;
    const int l15  = lane & 15;
    const int quad = lane >> 4;
    const int x0   = (quad ^ (l15 & 7)) * 8;         // h=0 swizzled seg offset (elements)

    int aoffs[4], boffs[4];
#pragma unroll
    for (int i = 0; i < 4; i++) {
        aoffs[i] = (wm + i * 16 + l15) * 64 + x0;
        boffs[i] = (wn + i * 16 + l15) * 64 + x0;
    }

    floatx4 acc[4][4];
#pragma unroll
    for (int i = 0; i < 4; i++)
#pragma unroll
        for (int j = 0; j < 4; j++) acc[i][j] = (floatx4){0.f, 0.f, 0.f, 0.f};

    for (int k0 = 0; k0 < D_; k0 += 64) {
#pragma unroll
        for (int w = 0; w < 4; w++) {
            gl_lds16(xb  + aoffW[w] + k0,                    &Asm[(w * 256 + tid) * 8]);
            gl_lds16(w1t + boff0 + (size_t)w * 32 * D_ + k0, &Bsm[(w * 256 + tid) * 8]);
        }
        __syncthreads();
        bf16x8 af[4], bfr[4];
#pragma unroll
        for (int i = 0; i < 4; i++) {                 // k-half 0
            af[i]  = *(const bf16x8*)&Asm[aoffs[i]];
            bfr[i] = *(const bf16x8*)&Bsm[boffs[i]];
        }
#pragma unroll
        for (int i = 0; i < 4; i++)
#pragma unroll
            for (int j = 0; j < 4; j++)
                acc[i][j] = __builtin_amdgcn_mfma_f32_16x16x32_bf16(af[i], bfr[j], acc[i][j], 0, 0, 0);
#pragma unroll
        for (int i = 0; i < 4; i++) {                 // k-half 1: seg offset = x0 ^ 4 -> elem ^ 32
            af[i]  = *(const bf16x8*)&Asm[aoffs[i] ^ 32];
            bfr[i] = *(const bf16x8*)&Bsm[boffs[i] ^ 32];
        }
#pragma unroll
        for (int i = 0; i < 4; i++)
#pragma unroll
            for (int j = 0; j < 4; j++)
                acc[i][j] = __builtin_amdgcn_mfma_f32_16x16x32_bf16(af[i], bfr[j], acc[i][j], 0, 0, 0);
        __syncthreads();
    }

    // epilogue: silu -> H (bf16). C/D layout: row = quad*4+r, col = lane&15 (m89-verified)
    unsigned short* Hbe = H + (size_t)be * KCAP * F_;
#pragma unroll
    for (int i = 0; i < 4; i++) {
#pragma unroll
        for (int r = 0; r < 4; r++) {
            int m = mt * 128 + wm + i * 16 + quad * 4 + r;
            unsigned short* hrow = Hbe + (size_t)m * F_ + nt * 128;
#pragma unroll
            for (int j = 0; j < 4; j++) {
                float v = acc[i][j][r];
                float sv = v / (1.f + __expf(-v));
                hrow[wn + j * 16 + l15] = f2b(sv);
            }
        }
    }
}

// ---------------- 5. GEMM2: xmlp[be] = H[be] @ w2[e]  (bf16 out, no atomics) ----------------
__global__ __launch_bounds__(256, 4) void gemm2_kernel(
    const unsigned short* __restrict__ H,    // [B*E][KCAP][F] bf16
    const unsigned short* __restrict__ w2t,  // [E][D][F] bf16
    unsigned short* __restrict__ xmlp)       // [B*E][KCAP][D] bf16
{
    const int g  = blockIdx.x;               // 1024 = 8 xcd * 8 b * 16 tiles
    const int e  = g & 7;                    // XCD id
    const int rr = g >> 3;
    const int b  = rr >> 4;
    const int t4 = rr & 15;
    const int be = b * 8 + e;
    const int mt = t4 & 1;          // 2 m-tiles
    const int nt = t4 >> 1;         // 8 n-tiles (1024/128)
    const int tid = threadIdx.x;

    __shared__ __align__(16) unsigned short Asm[128 * 64];
    __shared__ __align__(16) unsigned short Bsm[128 * 64];

    const int r8   = tid >> 3;
    const int kseg = (tid & 7) ^ (r8 & 7);
    const size_t aoff0 = ((size_t)be * KCAP + mt * 128 + r8) * F_ + kseg * 8;
    const size_t boff0 = ((size_t)e * D_ + nt * 128 + r8) * F_ + kseg * 8;

    const int lane = tid & 63;
    const int wv   = tid >> 6;
    const int wm   = (wv & 1) * 64;
    const int wn   = (wv >> 1) * 64;
    const int l15  = lane & 15;
    const int quad = lane >> 4;
    const int x0   = (quad ^ (l15 & 7)) * 8;

    int aoffs[4], boffs[4];
#pragma unroll
    for (int i = 0; i < 4; i++) {
        aoffs[i] = (wm + i * 16 + l15) * 64 + x0;
        boffs[i] = (wn + i * 16 + l15) * 64 + x0;
    }

    floatx4 acc[4][4];
#pragma unroll
    for (int i = 0; i < 4; i++)
#pragma unroll
        for (int j = 0; j < 4; j++) acc[i][j] = (floatx4){0.f, 0.f, 0.f, 0.f};

    for (int k0 = 0; k0 < F_; k0 += 64) {
#pragma unroll
        for (int w = 0; w < 4; w++) {
            gl_lds16(H   + aoff0 + (size_t)w * 32 * F_ + k0, &Asm[(w * 256 + tid) * 8]);
            gl_lds16(w2t + boff0 + (size_t)w * 32 * F_ + k0, &Bsm[(w * 256 + tid) * 8]);
        }
        __syncthreads();
        bf16x8 af[4], bfr[4];
#pragma unroll
        for (int i = 0; i < 4; i++) {
            af[i]  = *(const bf16x8*)&Asm[aoffs[i]];
            bfr[i] = *(const bf16x8*)&Bsm[boffs[i]];
        }
#pragma unroll
        for (int i = 0; i < 4; i++)
#pragma unroll
            for (int j = 0; j < 4; j++)
                acc[i][j] = __builtin_amdgcn_mfma_f32_16x16x32_bf16(af[i], bfr[j], acc[i][j], 0, 0, 0);
#pragma unroll
        for (int i = 0; i < 4; i++) {
            af[i]  = *(const bf16x8*)&Asm[aoffs[i] ^ 32];
            bfr[i] = *(const bf16x8*)&Bsm[boffs[i] ^ 32];
        }
#pragma unroll
        for (int i = 0; i < 4; i++)
#pragma unroll
            for (int j = 0; j < 4; j++)
                acc[i][j] = __builtin_amdgcn_mfma_f32_16x16x32_bf16(af[i], bfr[j], acc[i][j], 0, 0, 0);
        __syncthreads();
    }

    // epilogue: plain coalesced bf16 stores (combine kernel applies G and scatters)
    unsigned short* Xbe = xmlp + (size_t)be * KCAP * D_;
#pragma unroll
    for (int i = 0; i < 4; i++) {
#pragma unroll
        for (int r = 0; r < 4; r++) {
            int m = mt * 128 + wm + i * 16 + quad * 4 + r;
            unsigned short* orow = Xbe + (size_t)m * D_ + nt * 128;
#pragma unroll
            for (int j = 0; j < 4; j++)
                orow[wn + j * 16 + l15] = f2b(acc[i][j][r]);
        }
    }
}

// ---------------- 6. combine: out[b,s,:] = sum_e Pmap-hit G * xmlp-row (each token written once) -------
__global__ void combine_kernel(const unsigned short* __restrict__ xmlp, // [B*E][KCAP][D] bf16
                               const unsigned short* __restrict__ Pmap, // [B][S][E] slot+1
                               const float* __restrict__ G,             // [B*E][KCAP]
                               float* __restrict__ out) {               // [B][S][D] fp32
    int gid  = blockIdx.x * 256 + threadIdx.x;
    int wave = gid >> 6;                               // token id b*S+s
    int lane = gid & 63;
    int b = wave >> 10;
    float acc[16];
#pragma unroll
    for (int i = 0; i < 16; i++) acc[i] = 0.f;
    const unsigned short* pm = Pmap + (size_t)wave * E_;
#pragma unroll
    for (int e = 0; e < E_; e++) {
        int pe = pm[e];
        if (pe) {
            int beslot = (b * E_ + e) * KCAP + (pe - 1);
            float g = G[beslot];
            const unsigned short* rw = xmlp + (size_t)beslot * D_ + lane * 16;
            ushortx8 r0 = *(const ushortx8*)(rw);
            ushortx8 r1 = *(const ushortx8*)(rw + 8);
#pragma unroll
            for (int i = 0; i < 8; i++) {
                acc[i]     = fmaf(g, b2f(r0[i]), acc[i]);
                acc[8 + i] = fmaf(g, b2f(r1[i]), acc[8 + i]);
            }
        }
    }
    float* orow = out + (size_t)wave * D_ + lane * 16;
    ((float4*)orow)[0] = make_float4(acc[0],  acc[1],  acc[2],  acc[3]);
    ((float4*)orow)[1] = make_float4(acc[4],  acc[5],  acc[6],  acc[7]);
    ((float4*)orow)[2] = make_float4(acc[8],  acc[9],  acc[10], acc[11]);
    ((float4*)orow)[3] = make_float4(acc[12], acc[13], acc[14], acc[15]);
}

// ---------------- launch ----------------
extern "C" void kernel_launch(void* const* d_in, const int* in_sizes, int n_in,
                              void* d_out, int out_size, void* d_ws, size_t ws_size,
                              hipStream_t stream) {
    const float* x  = (const float*)d_in[0];
    const float* cw = (const float*)d_in[1];
    const float* w1 = (const float*)d_in[2];
    const float* w2 = (const float*)d_in[3];
    float* out = (float*)d_out;

    // workspace layout (bytes), total 151,519,232.
    // wT shared between w1t (gemm1) and w2t (gemm2) -- transpose of w2 runs AFTER gemm1.
    // R4 (1 MB partial-rank scratch) aliases the xmlp region: topk runs before gemm2 writes xmlp.
    char* ws = (char*)d_ws;
    float*          probs = (float*)(ws);                        //   0.26 MB  [B][E][S]
    int*            Ibuf  = (int*)(ws + 262144);                 //  64 KB     [B][E][256]
    float*          Gbuf  = (float*)(ws + 327680);               //  64 KB
    unsigned short* Pmap  = (unsigned short*)(ws + 393216);      // 128 KB     [B][S][E]
    unsigned short* xb    = (unsigned short*)(ws + 524288);      //  16.78 MB  x bf16
    unsigned short* wT    = (unsigned short*)(ws + 17301504);    //  33.55 MB  [E][F][D] then [E][D][F]
    unsigned short* Hbuf  = (unsigned short*)(ws + 50855936);    //  67.11 MB  [B*E][256][F]
    unsigned short* xmlp  = (unsigned short*)(ws + 117964800);   //  33.55 MB  [B*E][256][D]
    int*            R4    = (int*)xmlp;                          //   1 MB     [64*4][1024] (aliased)

    router_kernel<<<(B_ * S_ * 64) / 256, 256, 0, stream>>>(x, cw, probs, xb);
    topk_rank_kernel<<<B_ * E_ * 4, 256, 0, stream>>>(probs, R4);
    topk_finalize_kernel<<<B_ * E_, 256, 0, stream>>>(probs, R4, Ibuf, Gbuf, Pmap);
    transpose_cvt_kernel<<<dim3(F_ / 32, D_ / 32, E_), 256, 0, stream>>>(w1, wT, D_, F_);
    gemm1_kernel<<<B_ * E_ * 2 * (F_ / 128), 256, 0, stream>>>(xb, wT, Ibuf, Hbuf);
    transpose_cvt_kernel<<<dim3(D_ / 32, F_ / 32, E_), 256, 0, stream>>>(w2, wT, F_, D_);
    gemm2_kernel<<<B_ * E_ * 2 * (D_ / 128), 256, 0, stream>>>(Hbuf, wT, xmlp);
    combine_kernel<<<(B_ * S_ * 64) / 256, 256, 0, stream>>>(xmlp, Pmap, Gbuf, out);
}